// Round 5
// baseline (791.773 us; speedup 1.0000x reference)
//
#include <hip/hip_runtime.h>

// VectorQuantizer on MI355X — replicate numpy-fp32 rounding in the distance,
// so argmin matches the np reference's grid-quantized distances exactly.
// x: (32,256,32,32) fp32, codebook: (1024,256) fp32.
// Outputs concat: quantized (8388608 f32), vq_loss (1 f32), indices (32768 as f32).
//
// v6: pipe-balanced design.
//  - Per-CU accounting: FMA floor 262K cyc; v1's dual-LDS feed was 786K LDS
//    cyc (bound); v5's SMEM e-feed serialized on lgkmcnt (SMEM+DS share it).
//  - Thread tile 8m x 2k: one e-b128 feeds 8 m -> e-LDS instrs = FMA/32 =
//    197K cyc/CU, UNDER the FMA floor. e is the only LDS operand.
//  - z from global [d][m] (4m-broadcast quads); TM=32 -> 32KB x-tile, per-CU
//    z-traffic ~1MB via L1/L2 (no v4-style L2 thrash).
//  - e staged via global_load_lds (16B, no staging regs, vmcnt-counted),
//    double-buffered 2x16KB, stage-before-compute, 1 barrier/phase.
//  - LDS XOR swizzle quad = dq ^ ((k>>1)&7), applied on the global SOURCE
//    column at stage time + on the read address: reads are 2-way (free).
//    (row>>1)&7 is issue-invariant -> source perm is thread-constant.
//  - Registers: accd[8][2] f64 (32) + af 16 + e 8 + z 8 + best 16 + addr
//    ~= 112 <= 128 cap (v2/v3 proved the allocator refuses >128).
//  - Arithmetic bit-identical to v1: per-32-chunk fp32 fma chains (mul
//    start, d ascending), chunk sums to f64 ascending, same epilogue
//    rounding, strict-< earliest-k tie-break.

#define NUM_K 1024
#define DIM   256
#define HW    1024          // H*W
#define N_TOT 32768         // B*H*W
#define TM    32            // m rows per block
#define TK    128           // k-tile
#define DB    32            // d-chunk per phase (numpy chunk size)
#define NKT   (NUM_K / TK)  // 8
#define NDC   (DIM / DB)    // 8
#define NPH   (NKT * NDC)   // 64
#define LOSS_OFF 8388608
#define IDX_OFF  8388609

// numpy pairwise sum of squares over 256 elements, exact numpy order.
__device__ __forceinline__ float np_sumsq_256(const float* p, int stride) {
    float s[2];
    #pragma unroll
    for (int h = 0; h < 2; ++h) {
        const float* base = p + h * 128 * stride;
        float r[8];
        #pragma unroll
        for (int j = 0; j < 8; ++j) {
            float v = base[j * stride];
            r[j] = __fmul_rn(v, v);
        }
        for (int i = 8; i < 128; i += 8) {
            #pragma unroll
            for (int j = 0; j < 8; ++j) {
                float v = base[(i + j) * stride];
                r[j] = __fadd_rn(r[j], __fmul_rn(v, v));
            }
        }
        s[h] = __fadd_rn(__fadd_rn(__fadd_rn(r[0], r[1]), __fadd_rn(r[2], r[3])),
                         __fadd_rn(__fadd_rn(r[4], r[5]), __fadd_rn(r[6], r[7])));
    }
    return __fadd_rn(s[0], s[1]);
}

__global__ __launch_bounds__(256) void u2_kernel(const float* __restrict__ cb,
                                                 float* __restrict__ u2) {
    int k = blockIdx.x * 256 + threadIdx.x;     // 4 blocks x 256
    u2[k] = np_sumsq_256(cb + (size_t)k * DIM, 1);
}

typedef __attribute__((address_space(1))) const char GCHAR;
typedef __attribute__((address_space(3))) char LCHAR;

__global__ __launch_bounds__(256) void vq_main(const float* __restrict__ x,
                                               const float* __restrict__ cb,
                                               const float* __restrict__ u2,
                                               float* __restrict__ out) {
    __shared__ __align__(16) float eT[2 * TK * DB];   // 2 x 16 KB, [k][d] swizzled
    __shared__ float Ts_s[TM];
    __shared__ float red_v[4 * TM];
    __shared__ int   red_k[4 * TM];
    __shared__ int   bestk_s[TM];
    __shared__ float wsum[4];

    const int t  = threadIdx.x;
    const int g  = blockIdx.x;              // 1024 blocks
    const int n0 = g * TM;
    const int b  = n0 >> 10;                // /1024
    const int r0 = n0 & (HW - 1);
    const size_t xbase = (size_t)b * (DIM * HW) + r0;

    const int mg  = t & 3;                  // 4 m-groups
    const int m8  = mg * 8;                 // 8 m's per thread
    const int kg  = t >> 2;                 // 0..63 -> rows kg*2, kg*2+1
    const int qsh = (kg & 7) << 4;          // read-side swizzle XOR (bytes)
    const int erow = kg * 256;              // byte offset of row kg*2 (32 f/row)

    // staging constants: chunk c = iss*256 + t; row = c>>3 = iss*32 + (t>>3);
    // phys quad pd = t&7; swizzle s(row) = (row>>1)&7 = (t>>4)&7 (iss-invariant)
    const int srow = t >> 3;
    const int scol = 4 * ((t & 7) ^ ((t >> 4) & 7));
    const int wavebase = (t & 192) * 16;    // wave-uniform chunk base (bytes)

    // ---- numpy-order ||z||^2 per m (threads 0..31, coalesced across m) ----
    if (t < TM) Ts_s[t] = np_sumsq_256(x + xbase + t, HW);

    // ---- prologue: stage phase 0 into buf 0 ----
    {
        #pragma unroll
        for (int iss = 0; iss < 4; ++iss) {
            const float* src = cb + (size_t)(iss * 32 + srow) * DIM + scol;
            char* dst = (char*)eT + iss * 4096 + wavebase;
            __builtin_amdgcn_global_load_lds((GCHAR*)src, (LCHAR*)dst, 16, 0, 0);
        }
    }
    __syncthreads();

    float bv[8]; int bk[8];
    #pragma unroll
    for (int i = 0; i < 8; ++i) { bv[i] = 3.4e38f; bk[i] = 0; }

    for (int kt = 0; kt < NKT; ++kt) {
        const int k0 = kt * TK;
        double accd[8][2];
        #pragma unroll
        for (int i = 0; i < 8; ++i) { accd[i][0] = 0.0; accd[i][1] = 0.0; }

        for (int dc = 0; dc < NDC; ++dc) {
            const int p   = kt * NDC + dc;
            const int cur = p & 1;

            // stage next phase into the other buffer (loads land under FMAs)
            if (p + 1 < NPH) {
                const int k0n = ((p + 1) >> 3) * TK;
                const int d0n = ((p + 1) & 7) * DB;
                #pragma unroll
                for (int iss = 0; iss < 4; ++iss) {
                    const float* src = cb + (size_t)(k0n + iss * 32 + srow) * DIM + d0n + scol;
                    char* dst = (char*)eT + (cur ^ 1) * 16384 + iss * 4096 + wavebase;
                    __builtin_amdgcn_global_load_lds((GCHAR*)src, (LCHAR*)dst, 16, 0, 0);
                }
            }

            const int d0 = dc * DB;
            const char*  ebuf = (const char*)eT + cur * 16384 + erow;
            const float* zc   = x + xbase + (size_t)d0 * HW + m8;

            float af[8][2];
            #pragma unroll
            for (int dq = 0; dq < 8; ++dq) {
                const char* ea = ebuf + ((dq << 4) ^ qsh);
                float4 e0 = *(const float4*)(ea);          // row kg*2,   d-quad dq
                float4 e1 = *(const float4*)(ea + 128);    // row kg*2+1, d-quad dq
                #pragma unroll
                for (int dd = 0; dd < 4; ++dd) {
                    const float* zr = zc + (size_t)(dq * 4 + dd) * HW;
                    float4 z0 = *(const float4*)(zr);
                    float4 z1 = *(const float4*)(zr + 4);
                    float za[8] = {z0.x, z0.y, z0.z, z0.w, z1.x, z1.y, z1.z, z1.w};
                    float ee0 = ((const float*)&e0)[dd];
                    float ee1 = ((const float*)&e1)[dd];
                    #pragma unroll
                    for (int i = 0; i < 8; ++i) {
                        if (dq == 0 && dd == 0) {          // fma(a,b,0)==a*b
                            af[i][0] = __fmul_rn(za[i], ee0);
                            af[i][1] = __fmul_rn(za[i], ee1);
                        } else {
                            af[i][0] = fmaf(za[i], ee0, af[i][0]);
                            af[i][1] = fmaf(za[i], ee1, af[i][1]);
                        }
                    }
                }
            }
            #pragma unroll
            for (int i = 0; i < 8; ++i) {
                accd[i][0] += (double)af[i][0];
                accd[i][1] += (double)af[i][1];
            }
            __syncthreads();   // drains stage (vmcnt) + eT reads; swap buffers
        }

        // ---- kt epilogue: d = fl32( fl32(T_n + U_k) - 2*fl32(dot) ) ----
        const float u0 = u2[k0 + kg * 2];
        const float u1 = u2[k0 + kg * 2 + 1];
        #pragma unroll
        for (int j = 0; j < 2; ++j) {
            const int   kk = k0 + kg * 2 + j;
            const float uj = j ? u1 : u0;
            #pragma unroll
            for (int i = 0; i < 8; ++i) {
                float m32 = (float)accd[i][j];              // fl32(dot)
                float c   = __fmul_rn(2.0f, m32);           // exact
                float t1  = __fadd_rn(Ts_s[m8 + i], uj);    // fl32(T+U)
                float d32 = __fsub_rn(t1, c);               // fl32(t1-c)
                // strict < keeps the earliest k (ks ascend within a thread)
                if (d32 < bv[i]) { bv[i] = d32; bk[i] = kk; }
            }
        }
    }

    // ---- argmin: reduce across kg within the wave (same-m cosets mod 4) ----
    #pragma unroll
    for (int i = 0; i < 8; ++i) {
        float v = bv[i]; int k = bk[i];
        #pragma unroll
        for (int off = 4; off < 64; off <<= 1) {
            float ov = __shfl_xor(v, off, 64);
            int   ok = __shfl_xor(k, off, 64);
            if (ov < v || (ov == v && ok < k)) { v = ov; k = ok; }
        }
        bv[i] = v; bk[i] = k;
    }
    const int wv = t >> 6;                  // wave id 0..3
    if ((t & 63) < 4) {                     // one lane per m-group per wave
        #pragma unroll
        for (int i = 0; i < 8; ++i) {
            red_v[wv * TM + m8 + i] = bv[i];
            red_k[wv * TM + m8 + i] = bk[i];
        }
    }
    __syncthreads();
    if (t < TM) {
        float bvf = red_v[t]; int bkf = red_k[t];
        #pragma unroll
        for (int q = 1; q < 4; ++q) {
            float v = red_v[q * TM + t]; int k = red_k[q * TM + t];
            if (v < bvf || (v == bvf && k < bkf)) { bvf = v; bkf = k; }
        }
        bestk_s[t] = bkf;
        out[IDX_OFF + n0 + t] = (float)bkf;   // indices as float
    }
    __syncthreads();

    // ---- epilogue: quantized output + fused loss (x re-read, L2-hot) ----
    float lsum = 0.f;
    {
        const int m  = t & 31;
        const int kq = bestk_s[m];
        const float* crow = cb + (size_t)kq * DIM;
        for (int c = (t >> 5); c < DIM; c += 8) {
            float qv = crow[c];
            float xv = x[xbase + (size_t)c * HW + m];
            float d  = qv - xv;
            lsum = fmaf(d, d, lsum);
            out[xbase + (size_t)c * HW + m] = qv;
        }
    }
    #pragma unroll
    for (int off = 32; off > 0; off >>= 1) lsum += __shfl_down(lsum, off, 64);
    if ((t & 63) == 0) wsum[wv] = lsum;
    __syncthreads();
    if (t == 0) {
        float s = (wsum[0] + wsum[1]) + (wsum[2] + wsum[3]);
        // vq_loss = q_latent + 0.25*e_latent, both equal mean((q-x)^2)
        atomicAdd(out + LOSS_OFF, s * (1.25f / 8388608.0f));
    }
}

extern "C" void kernel_launch(void* const* d_in, const int* in_sizes, int n_in,
                              void* d_out, int out_size, void* d_ws, size_t ws_size,
                              hipStream_t stream) {
    const float* x  = (const float*)d_in[0];
    const float* cb = (const float*)d_in[1];
    float* out = (float*)d_out;
    float* u2  = (float*)d_ws;          // 4 KB scratch (numpy-order ||e||^2)

    // zero the loss slot (atomicAdd target); graph-capture-safe
    hipMemsetAsync(out + LOSS_OFF, 0, sizeof(float), stream);
    u2_kernel<<<NUM_K / 256, 256, 0, stream>>>(cb, u2);
    vq_main<<<N_TOT / TM, 256, 0, stream>>>(x, cb, u2, out);
}